// Round 7
// baseline (176.005 us; speedup 1.0000x reference)
//
#include <hip/hip_runtime.h>
#include <math.h>

#define EMBED 512
#define NQ 8
#define SEQ 2048
#define NB 8
#define LOG2E 1.4426950408889634f

typedef float vfloat4 __attribute__((ext_vector_type(4)));  // clang vector: ok for nontemporal builtins

// ---------------------------------------------------------------------------
// k1: rotT[b][q][i] = sum_e x[b][i][e] * R[e][q]
// R transposed through LDS (stride 516: 16B-aligned rows, conflict-free b128).
// Thread (q = tid&7, rslot = tid>>3) does one K=512 dot with vfloat4;
// 4 independent accumulator chains hide fma latency.
// ---------------------------------------------------------------------------
#define RPAD 516

__global__ __launch_bounds__(256) void qa_rot(
    const float* __restrict__ x, const float* __restrict__ R,
    float* __restrict__ rotT) {
    __shared__ float rt[NQ * RPAD];
#pragma unroll
    for (int m = 0; m < (EMBED * NQ) / 256; ++m) {
        int f = threadIdx.x + m * 256;
        rt[(f & 7) * RPAD + (f >> 3)] = R[f];
    }
    __syncthreads();

    const int q = threadIdx.x & 7;
    const int rslot = threadIdx.x >> 3;           // 0..31
    const int b = blockIdx.x >> 6;                // 64 blocks per batch
    const int i = ((blockIdx.x & 63) << 5) + rslot;

    const vfloat4* __restrict__ xr =
        (const vfloat4*)(x + ((size_t)b * SEQ + i) * EMBED);
    const vfloat4* __restrict__ rr = (const vfloat4*)(rt + q * RPAD);

    vfloat4 acc = {0.f, 0.f, 0.f, 0.f};           // 4 independent chains
#pragma unroll 8
    for (int m = 0; m < EMBED / 4; ++m) {
        acc += xr[m] * rr[m];                     // vector fma (v_pk_fma_f32)
    }
    rotT[(size_t)b * (NQ * SEQ) + (size_t)q * SEQ + i] =
        (acc.x + acc.y) + (acc.z + acc.w);
}

// ---------------------------------------------------------------------------
// k2: scores[b][i][j] = sigmoid(rot_i . rot_j) / rowsum — single pass,
// LDS-staged, 512-thread blocks (16 waves/CU at 2 blocks/CU — R6's win).
// NEW vs R6: TI=4 rows/wave with a j-SPLIT — wave pair (2g, 2g+1) owns the
// same 4 rows, each covering one 1024-j half. Halves rj LDS traffic per
// output element (16 B -> 8 B) and per-element loop overhead. Rowsums are
// combined across the wave pair through a 128 B LDS patch.
// VGPR budget at the (512,4) 128-reg cap: pv 64 + ri 32 + s 16 + rj 4 ≈ 120.
// ---------------------------------------------------------------------------
#define K2_THREADS 512
#define TI 4
#define ROWS_PER_BLOCK 16   // 4 row-groups * TI

__global__ __launch_bounds__(K2_THREADS, 4) void qa_scores(
    const float* __restrict__ rotT, float* __restrict__ out) {
    __shared__ float lds[NQ * SEQ];               // 64 KiB, [q][j]
    __shared__ float red[8][TI];                  // cross-wave rowsum patch
    const int b = blockIdx.x >> 7;                // 128 blocks per batch
    const int i0blk = (blockIdx.x & 127) * ROWS_PER_BLOCK;
    const float* __restrict__ rt = rotT + (size_t)b * (NQ * SEQ);

    // Stage rotT[b] (16384 floats) cooperatively, coalesced 16B.
    {
        const vfloat4* __restrict__ src = (const vfloat4*)rt;
        vfloat4* dst = (vfloat4*)lds;
#pragma unroll
        for (int m = 0; m < (NQ * SEQ / 4) / K2_THREADS; ++m)
            dst[threadIdx.x + m * K2_THREADS] = src[threadIdx.x + m * K2_THREADS];
    }
    __syncthreads();

    const int wave = threadIdx.x >> 6;            // 0..7
    const int lane = threadIdx.x & 63;
    const int rowgrp = wave >> 1;                 // 0..3
    const int half = wave & 1;                    // j-half
    const int i0 = i0blk + rowgrp * TI;
    const int jbase = half * (SEQ / 2);

    // rot_i for this wave's 4 rows (broadcast LDS reads).
    float ri[TI][NQ];
#pragma unroll
    for (int r = 0; r < TI; ++r)
#pragma unroll
        for (int q = 0; q < NQ; ++q)
            ri[r][q] = lds[q * SEQ + i0 + r];

    // 4 tiles of 256 j in this wave's half; lane owns 4 consecutive j.
    vfloat4 pv[4][TI];                             // 64 VGPRs of probs
    float rsum[TI] = {0.f, 0.f, 0.f, 0.f};

#pragma unroll
    for (int t = 0; t < 4; ++t) {
        vfloat4 s[TI];
#pragma unroll
        for (int r = 0; r < TI; ++r) s[r] = (vfloat4){0.f, 0.f, 0.f, 0.f};
#pragma unroll
        for (int q = 0; q < NQ; ++q) {            // q-outer: 1 rj live
            vfloat4 rj = *((const vfloat4*)(lds + q * SEQ + jbase + t * 256) + lane);
#pragma unroll
            for (int r = 0; r < TI; ++r)
                s[r] += rj * ri[r][q];            // vector fma / v_pk_fma_f32
        }
#pragma unroll
        for (int r = 0; r < TI; ++r) {
            vfloat4 p;
            p.x = __builtin_amdgcn_rcpf(1.f + __builtin_amdgcn_exp2f(-s[r].x * LOG2E));
            p.y = __builtin_amdgcn_rcpf(1.f + __builtin_amdgcn_exp2f(-s[r].y * LOG2E));
            p.z = __builtin_amdgcn_rcpf(1.f + __builtin_amdgcn_exp2f(-s[r].z * LOG2E));
            p.w = __builtin_amdgcn_rcpf(1.f + __builtin_amdgcn_exp2f(-s[r].w * LOG2E));
            pv[t][r] = p;
            rsum[r] += (p.x + p.y) + (p.z + p.w);
        }
    }

    // Butterfly reduce each half-rowsum over 64 lanes.
#pragma unroll
    for (int r = 0; r < TI; ++r) {
#pragma unroll
        for (int off = 32; off > 0; off >>= 1)
            rsum[r] += __shfl_xor(rsum[r], off);
    }
    // Combine the two j-halves across the wave pair via LDS.
    if (lane == 0) {
#pragma unroll
        for (int r = 0; r < TI; ++r) red[wave][r] = rsum[r];
    }
    __syncthreads();
#pragma unroll
    for (int r = 0; r < TI; ++r)
        rsum[r] = __builtin_amdgcn_rcpf(red[rowgrp * 2][r] + red[rowgrp * 2 + 1][r]);

    // Normalize from registers and store (dwordx4, nontemporal).
#pragma unroll
    for (int r = 0; r < TI; ++r) {
        float* __restrict__ orow = out + ((size_t)b * SEQ + i0 + r) * SEQ + jbase;
#pragma unroll
        for (int t = 0; t < 4; ++t) {
            vfloat4 v = pv[t][r] * rsum[r];
            __builtin_nontemporal_store(v, (vfloat4*)(orow + t * 256) + lane);
        }
    }
}

// ---------------------------------------------------------------------------
extern "C" void kernel_launch(void* const* d_in, const int* in_sizes, int n_in,
                              void* d_out, int out_size, void* d_ws, size_t ws_size,
                              hipStream_t stream) {
    const float* x        = (const float*)d_in[0];  // (8, 2048, 512) fp32
    const float* rotation = (const float*)d_in[1];  // (512, 8) fp32
    float* out = (float*)d_out;                     // (8, 2048, 2048) fp32

    float* rotT = (float*)d_ws;                     // 8 x 8 x 2048 = 512 KiB

    qa_rot<<<NB * 64, 256, 0, stream>>>(x, rotation, rotT);
    qa_scores<<<NB * 128, K2_THREADS, 0, stream>>>(rotT, out);
}

// Round 8
// 170.289 us; speedup vs baseline: 1.0336x; 1.0336x over previous
//
#include <hip/hip_runtime.h>
#include <math.h>

#define EMBED 512
#define NQ 8
#define SEQ 2048
#define NB 8
#define LOG2E 1.4426950408889634f

typedef float vfloat4 __attribute__((ext_vector_type(4)));  // clang vector: ok for nontemporal builtins

// ---------------------------------------------------------------------------
// k1: rotT[b][q][i] = sum_e x[b][i][e] * R[e][q]
// R transposed through LDS (stride 516: 16B-aligned rows, conflict-free b128).
// Thread (q = tid&7, rslot = tid>>3) does one K=512 dot with vfloat4;
// 4 independent accumulator chains hide fma latency. Plain (cached) store of
// rotT — k2 re-reads it immediately, keep it in L2.
// ~6 µs: bound by the 32 MiB x read.
// ---------------------------------------------------------------------------
#define RPAD 516

__global__ __launch_bounds__(256) void qa_rot(
    const float* __restrict__ x, const float* __restrict__ R,
    float* __restrict__ rotT) {
    __shared__ float rt[NQ * RPAD];
#pragma unroll
    for (int m = 0; m < (EMBED * NQ) / 256; ++m) {
        int f = threadIdx.x + m * 256;
        rt[(f & 7) * RPAD + (f >> 3)] = R[f];
    }
    __syncthreads();

    const int q = threadIdx.x & 7;
    const int rslot = threadIdx.x >> 3;           // 0..31
    const int b = blockIdx.x >> 6;                // 64 blocks per batch
    const int i = ((blockIdx.x & 63) << 5) + rslot;

    const vfloat4* __restrict__ xr =
        (const vfloat4*)(x + ((size_t)b * SEQ + i) * EMBED);
    const vfloat4* __restrict__ rr = (const vfloat4*)(rt + q * RPAD);

    vfloat4 acc = {0.f, 0.f, 0.f, 0.f};           // 4 independent chains
#pragma unroll 8
    for (int m = 0; m < EMBED / 4; ++m) {
        acc += xr[m] * rr[m];                     // packed fma
    }
    rotT[(size_t)b * (NQ * SEQ) + (size_t)q * SEQ + i] =
        (acc.x + acc.y) + (acc.z + acc.w);
}

// ---------------------------------------------------------------------------
// k2: scores[b][i][j] = sigmoid(rot_i . rot_j) / rowsum — single pass,
// LDS-staged, 512-thread blocks: 8 waves x TI=2 = 16 rows/block,
// 128 blocks/batch, grid 1024. 64 KiB LDS -> 2 blocks/CU -> 16 waves/CU;
// store bursts of some waves overlap compute of others. q-outer inner loop
// keeps rj live range at one vfloat4: ~107 VGPRs, no spill at the (512,4)
// 128-reg cap. TI=4 variants are register-boxed (R7: 130 regs -> spill,
// +5 µs) — do not raise TI without removing pv.
// ---------------------------------------------------------------------------
#define K2_THREADS 512
#define TI 2
#define ROWS_PER_BLOCK 16   // 8 waves * TI

__global__ __launch_bounds__(K2_THREADS, 4) void qa_scores(
    const float* __restrict__ rotT, float* __restrict__ out) {
    __shared__ float lds[NQ * SEQ];               // 64 KiB, [q][j]
    const int b = blockIdx.x >> 7;                // 128 blocks per batch
    const int i0blk = (blockIdx.x & 127) * ROWS_PER_BLOCK;
    const float* __restrict__ rt = rotT + (size_t)b * (NQ * SEQ);

    // Stage rotT[b] (16384 floats) cooperatively, coalesced 16B.
    {
        const vfloat4* __restrict__ src = (const vfloat4*)rt;
        vfloat4* dst = (vfloat4*)lds;
#pragma unroll
        for (int m = 0; m < (NQ * SEQ / 4) / K2_THREADS; ++m)
            dst[threadIdx.x + m * K2_THREADS] = src[threadIdx.x + m * K2_THREADS];
    }
    __syncthreads();

    const int wave = threadIdx.x >> 6;            // 0..7
    const int lane = threadIdx.x & 63;
    const int i0 = i0blk + wave * TI;

    // rot_i for this wave's 2 rows (broadcast LDS reads).
    float ri[TI][NQ];
#pragma unroll
    for (int r = 0; r < TI; ++r)
#pragma unroll
        for (int q = 0; q < NQ; ++q)
            ri[r][q] = lds[q * SEQ + i0 + r];

    // 8 tiles of 256 j; lane owns j = t*256 + 4*lane .. +3.
    vfloat4 pv[8][TI];                             // 64 VGPRs of probs
    float rsum[TI] = {0.f, 0.f};

#pragma unroll
    for (int t = 0; t < 8; ++t) {
        vfloat4 s[TI];
#pragma unroll
        for (int r = 0; r < TI; ++r) s[r] = (vfloat4){0.f, 0.f, 0.f, 0.f};
        // q-outer: one rj vfloat4 live at a time (register budget).
#pragma unroll
        for (int q = 0; q < NQ; ++q) {
            vfloat4 rj = *((const vfloat4*)(lds + q * SEQ + t * 256) + lane);
#pragma unroll
            for (int r = 0; r < TI; ++r)
                s[r] += rj * ri[r][q];            // packed fma
        }
#pragma unroll
        for (int r = 0; r < TI; ++r) {
            vfloat4 p;
            p.x = __builtin_amdgcn_rcpf(1.f + __builtin_amdgcn_exp2f(-s[r].x * LOG2E));
            p.y = __builtin_amdgcn_rcpf(1.f + __builtin_amdgcn_exp2f(-s[r].y * LOG2E));
            p.z = __builtin_amdgcn_rcpf(1.f + __builtin_amdgcn_exp2f(-s[r].z * LOG2E));
            p.w = __builtin_amdgcn_rcpf(1.f + __builtin_amdgcn_exp2f(-s[r].w * LOG2E));
            pv[t][r] = p;
            rsum[r] += (p.x + p.y) + (p.z + p.w);
        }
    }

    // Butterfly reduce rowsums over 64 lanes; keep inverse.
#pragma unroll
    for (int r = 0; r < TI; ++r) {
#pragma unroll
        for (int off = 32; off > 0; off >>= 1)
            rsum[r] += __shfl_xor(rsum[r], off);
        rsum[r] = __builtin_amdgcn_rcpf(rsum[r]);
    }

    // Normalize from registers and store (dwordx4, nontemporal).
#pragma unroll
    for (int r = 0; r < TI; ++r) {
        float* __restrict__ orow = out + ((size_t)b * SEQ + i0 + r) * SEQ;
#pragma unroll
        for (int t = 0; t < 8; ++t) {
            vfloat4 v = pv[t][r] * rsum[r];
            __builtin_nontemporal_store(v, (vfloat4*)(orow + t * 256) + lane);
        }
    }
}

// ---------------------------------------------------------------------------
extern "C" void kernel_launch(void* const* d_in, const int* in_sizes, int n_in,
                              void* d_out, int out_size, void* d_ws, size_t ws_size,
                              hipStream_t stream) {
    const float* x        = (const float*)d_in[0];  // (8, 2048, 512) fp32
    const float* rotation = (const float*)d_in[1];  // (512, 8) fp32
    float* out = (float*)d_out;                     // (8, 2048, 2048) fp32

    float* rotT = (float*)d_ws;                     // 8 x 8 x 2048 = 512 KiB

    qa_rot<<<NB * 64, 256, 0, stream>>>(x, rotation, rotT);
    qa_scores<<<NB * 128, K2_THREADS, 0, stream>>>(rotT, out);
}